// Round 5
// baseline (469.612 us; speedup 1.0000x reference)
//
#include <hip/hip_runtime.h>
#include <hip/hip_bf16.h>

#define KNBR 20

// ---- runtime index-width detection ----
// nbr has 2,000,000 entries uniform in [0,100000) (< 2^17, non-negative).
// If pushed as int64: odd 32-bit words are high-words, ALL zero.
// If pushed as int32: odd words are uniform values; P(8 words all 0) ~ 1e-40.
__device__ __forceinline__ bool idx_is64(const unsigned int* w) {
    return (w[1] | w[3] | w[5] | w[7] | w[9] | w[11] | w[13] | w[15]) == 0u;
}
__device__ __forceinline__ int idx_at(const int* p, bool is64, long long i) {
    // int64 low word of a value in [-1, 2^31) reinterprets correctly as int32
    return is64 ? p[2 * i] : p[i];
}

// ---------------- K0: sentinel — fill d_out with fp32 3.0 ----------------
// Diagnostic: if final absmax ~= 3.0, this ran but later kernels didn't.
// Overwritten by k_normalize when the pipeline works. Deterministic.
__global__ void __launch_bounds__(256) k_sentinel(float* __restrict__ out, int n4) {
    int i = blockIdx.x * 256 + threadIdx.x;
    if (i < n4) ((float4*)out)[i] = make_float4(3.f, 3.f, 3.f, 3.f);
}

// ---------------- K1: gather 20 neighbor rows, mean -> ws ----------------
// one wave per output row; lane handles 4 columns (float4).
__global__ void __launch_bounds__(256) k_gather_mean(
    const float* __restrict__ X, const int* __restrict__ sub_nodes,
    const int* __restrict__ nbr, const int* __restrict__ g2s,
    float* __restrict__ mean, int M)
{
    const bool is64 = idx_is64((const unsigned int*)nbr);
    const int lane = threadIdx.x & 63;
    const int row = (blockIdx.x << 2) + (threadIdx.x >> 6);
    if (row >= M) return;
    const int g = idx_at(sub_nodes, is64, row);
    int s_my = row;
    if (lane < KNBR) {
        int nid = idx_at(nbr, is64, (long long)g * KNBR + lane);
        int s   = idx_at(g2s, is64, nid);
        s_my = (s < 0) ? row : s;
    }
    const float4* Xv = (const float4*)X;
    float4 acc = make_float4(0.f, 0.f, 0.f, 0.f);
    #pragma unroll
    for (int k = 0; k < KNBR; ++k) {
        int sk = __shfl(s_my, k, 64);
        float4 v = Xv[(size_t)sk * 64 + lane];
        acc.x += v.x; acc.y += v.y; acc.z += v.z; acc.w += v.w;
    }
    const float inv = 1.0f / (float)KNBR;
    acc.x *= inv; acc.y *= inv; acc.z *= inv; acc.w *= inv;
    ((float4*)mean)[(size_t)row * 64 + lane] = acc;
}

// ---------------- K2: C = relu(A @ B^T + bias) ----------------
// A = [A0 | A1], each half 256 cols (A1 unused when KTOT==256).
// B is [256, KTOT] fp32 row-major. C is [M, 256] fp32.
// Tile 128x128, BK=16, 256 threads, 8x8 per thread.
__global__ void __launch_bounds__(256) k_gemm_relu(
    const float* __restrict__ A0, const float* __restrict__ A1,
    const float* __restrict__ B, const float* __restrict__ bias,
    float* __restrict__ C, int M, int KTOT)
{
    __shared__ float As[16][128];
    __shared__ float Bs[16][128];
    const int t  = threadIdx.x;
    const int m0 = blockIdx.x * 128;
    const int n0 = blockIdx.y * 128;
    const int lr = t >> 2;          // 0..63
    const int lk = (t & 3) << 2;    // 0,4,8,12
    const int tx = t & 15;          // n-dir
    const int ty = t >> 4;          // m-dir

    float acc[8][8];
    #pragma unroll
    for (int i = 0; i < 8; ++i)
        #pragma unroll
        for (int j = 0; j < 8; ++j) acc[i][j] = 0.f;

    for (int k0 = 0; k0 < KTOT; k0 += 16) {
        const int kg = k0 + lk;
        int r0 = m0 + lr;       r0 = (r0 < M) ? r0 : (M - 1);
        int r1 = m0 + lr + 64;  r1 = (r1 < M) ? r1 : (M - 1);
        const float* Asrc = (kg >= 256) ? A1 : A0;
        const int    kc   = (kg >= 256) ? (kg - 256) : kg;
        const float4 av0 = *(const float4*)(Asrc + (size_t)r0 * 256 + kc);
        const float4 av1 = *(const float4*)(Asrc + (size_t)r1 * 256 + kc);
        const float4 bv0 = *(const float4*)(B + (size_t)(n0 + lr) * KTOT + kg);
        const float4 bv1 = *(const float4*)(B + (size_t)(n0 + lr + 64) * KTOT + kg);

        __syncthreads();
        As[lk + 0][lr] = av0.x; As[lk + 1][lr] = av0.y;
        As[lk + 2][lr] = av0.z; As[lk + 3][lr] = av0.w;
        As[lk + 0][lr + 64] = av1.x; As[lk + 1][lr + 64] = av1.y;
        As[lk + 2][lr + 64] = av1.z; As[lk + 3][lr + 64] = av1.w;
        Bs[lk + 0][lr] = bv0.x; Bs[lk + 1][lr] = bv0.y;
        Bs[lk + 2][lr] = bv0.z; Bs[lk + 3][lr] = bv0.w;
        Bs[lk + 0][lr + 64] = bv1.x; Bs[lk + 1][lr + 64] = bv1.y;
        Bs[lk + 2][lr + 64] = bv1.z; Bs[lk + 3][lr + 64] = bv1.w;
        __syncthreads();

        #pragma unroll
        for (int k = 0; k < 16; ++k) {
            const float4 a0 = *(const float4*)&As[k][ty * 8];
            const float4 a1 = *(const float4*)&As[k][ty * 8 + 4];
            const float4 b0 = *(const float4*)&Bs[k][tx * 8];
            const float4 b1 = *(const float4*)&Bs[k][tx * 8 + 4];
            const float a[8] = {a0.x, a0.y, a0.z, a0.w, a1.x, a1.y, a1.z, a1.w};
            const float b[8] = {b0.x, b0.y, b0.z, b0.w, b1.x, b1.y, b1.z, b1.w};
            #pragma unroll
            for (int i = 0; i < 8; ++i)
                #pragma unroll
                for (int j = 0; j < 8; ++j)
                    acc[i][j] = fmaf(a[i], b[j], acc[i][j]);
        }
    }

    #pragma unroll
    for (int i = 0; i < 8; ++i) {
        const int row = m0 + ty * 8 + i;
        if (row >= M) continue;
        const int col = n0 + tx * 8;
        float4 o0, o1;
        o0.x = acc[i][0] + bias[col + 0]; o0.y = acc[i][1] + bias[col + 1];
        o0.z = acc[i][2] + bias[col + 2]; o0.w = acc[i][3] + bias[col + 3];
        o1.x = acc[i][4] + bias[col + 4]; o1.y = acc[i][5] + bias[col + 5];
        o1.z = acc[i][6] + bias[col + 6]; o1.w = acc[i][7] + bias[col + 7];
        o0.x = o0.x > 0.f ? o0.x : 0.f; o0.y = o0.y > 0.f ? o0.y : 0.f;
        o0.z = o0.z > 0.f ? o0.z : 0.f; o0.w = o0.w > 0.f ? o0.w : 0.f;
        o1.x = o1.x > 0.f ? o1.x : 0.f; o1.y = o1.y > 0.f ? o1.y : 0.f;
        o1.z = o1.z > 0.f ? o1.z : 0.f; o1.w = o1.w > 0.f ? o1.w : 0.f;
        *(float4*)(C + (size_t)row * 256 + col)     = o0;
        *(float4*)(C + (size_t)row * 256 + col + 4) = o1;
    }
}

// ---------------- K3: row L2-normalize, fp32 -> fp32 ----------------
__global__ void __launch_bounds__(256) k_normalize(
    const float* __restrict__ P, float* __restrict__ out, int M)
{
    const int lane = threadIdx.x & 63;
    const int row = (blockIdx.x << 2) + (threadIdx.x >> 6);
    if (row >= M) return;
    const float4 v = ((const float4*)P)[(size_t)row * 64 + lane];
    float ss = v.x * v.x + v.y * v.y + v.z * v.z + v.w * v.w;
    #pragma unroll
    for (int o = 32; o > 0; o >>= 1)
        ss += __shfl_xor(ss, o, 64);
    const float norm = sqrtf(ss);
    const float scale = 1.0f / fmaxf(norm, 1e-12f);
    float4 u;
    u.x = v.x * scale; u.y = v.y * scale; u.z = v.z * scale; u.w = v.w * scale;
    ((float4*)out)[(size_t)row * 64 + lane] = u;
}

extern "C" void kernel_launch(void* const* d_in, const int* in_sizes, int n_in,
                              void* d_out, int out_size, void* d_ws, size_t ws_size,
                              hipStream_t stream)
{
    const float* X         = (const float*)d_in[0];
    const int*   sub_nodes = (const int*)d_in[1];
    const int*   nbr       = (const int*)d_in[2];
    const int*   g2s       = (const int*)d_in[3];
    const float* Wn        = (const float*)d_in[4];
    const float* bn        = (const float*)d_in[5];
    const float* Wf        = (const float*)d_in[6];
    const float* bfin      = (const float*)d_in[7];
    float*       out       = (float*)d_out;

    const int M = out_size / 256;            // 50000 rows

    float* mean = (float*)d_ws;              // [M,256] fp32
    float* h    = mean + (size_t)M * 256;    // [M,256] fp32
    float* pre  = mean;                      // GEMM2 output reuses mean buffer

    dim3 b256(256);

    const int n4 = out_size / 4;
    k_sentinel<<<(n4 + 255) / 256, b256, 0, stream>>>(out, n4);

    const int rowBlocks = (M + 3) / 4;
    k_gather_mean<<<rowBlocks, b256, 0, stream>>>(X, sub_nodes, nbr, g2s, mean, M);

    dim3 g1((M + 127) / 128, 2);
    k_gemm_relu<<<g1, b256, 0, stream>>>(mean, nullptr, Wn, bn, h, M, 256);
    k_gemm_relu<<<g1, b256, 0, stream>>>(X, h, Wf, bfin, pre, M, 512);

    k_normalize<<<rowBlocks, b256, 0, stream>>>(pre, out, M);
}

// Round 6
// 281.416 us; speedup vs baseline: 1.6687x; 1.6687x over previous
//
#include <hip/hip_runtime.h>
#include <hip/hip_bf16.h>

#define KNBR 20

typedef unsigned short u16;
typedef __attribute__((ext_vector_type(8))) short bf16x8;   // 8 bf16 = 4 VGPR
typedef __attribute__((ext_vector_type(4))) float f32x4;    // MFMA C/D frag

// ---- runtime index-width detection (proven in round 5) ----
__device__ __forceinline__ bool idx_is64(const unsigned int* w) {
    return (w[1] | w[3] | w[5] | w[7] | w[9] | w[11] | w[13] | w[15]) == 0u;
}
__device__ __forceinline__ int idx_at(const int* p, bool is64, long long i) {
    return is64 ? p[2 * i] : p[i];
}

__device__ __forceinline__ u16 f2bf(float x) {
    union { __hip_bfloat16 b; u16 u; } cv;
    cv.b = __float2bfloat16(x);
    return cv.u;
}

// ---------------- K0: cast weights fp32 -> bf16 (tiny) ----------------
__global__ void __launch_bounds__(256) k_cast_w(
    const float* __restrict__ Wn, const float* __restrict__ Wf,
    u16* __restrict__ Wnb, u16* __restrict__ Wfb)
{
    int i = blockIdx.x * 256 + threadIdx.x;      // 196608 total
    if (i < 65536)       Wnb[i] = f2bf(Wn[i]);
    else if (i < 196608) Wfb[i - 65536] = f2bf(Wf[i - 65536]);
}

// ---------------- K1: gather-mean -> bf16 mean; also X -> bf16 copy ----------------
// one wave per row; lane owns 4 cols.
__global__ void __launch_bounds__(256) k_gather_mean(
    const float* __restrict__ X, const int* __restrict__ sub_nodes,
    const int* __restrict__ nbr, const int* __restrict__ g2s,
    u16* __restrict__ Xb, u16* __restrict__ mean_b, int M)
{
    const bool is64 = idx_is64((const unsigned int*)nbr);
    const int lane = threadIdx.x & 63;
    const int row = (blockIdx.x << 2) + (threadIdx.x >> 6);
    if (row >= M) return;
    const int g = idx_at(sub_nodes, is64, row);
    int s_my = row;
    if (lane < KNBR) {
        int nid = idx_at(nbr, is64, (long long)g * KNBR + lane);
        int s   = idx_at(g2s, is64, nid);
        s_my = (s < 0) ? row : s;
    }
    const float4* Xv = (const float4*)X;

    // own row -> bf16 copy (A-half 0 of GEMM2)
    float4 xo = Xv[(size_t)row * 64 + lane];
    ushort4 xb;
    xb.x = f2bf(xo.x); xb.y = f2bf(xo.y); xb.z = f2bf(xo.z); xb.w = f2bf(xo.w);
    ((ushort4*)Xb)[(size_t)row * 64 + lane] = xb;

    float4 acc = make_float4(0.f, 0.f, 0.f, 0.f);
    #pragma unroll
    for (int k = 0; k < KNBR; ++k) {
        int sk = __shfl(s_my, k, 64);
        float4 v = Xv[(size_t)sk * 64 + lane];
        acc.x += v.x; acc.y += v.y; acc.z += v.z; acc.w += v.w;
    }
    const float inv = 1.0f / (float)KNBR;
    ushort4 mb;
    mb.x = f2bf(acc.x * inv); mb.y = f2bf(acc.y * inv);
    mb.z = f2bf(acc.z * inv); mb.w = f2bf(acc.w * inv);
    ((ushort4*)mean_b)[(size_t)row * 64 + lane] = mb;
}

// ---------------- K2/K3: MFMA GEMM  C = relu(A @ W^T + bias) ----------------
// A bf16 [M,KTOT] as halves A0|A1 (row stride 256 each); W bf16 [256,KTOT].
// No LDS staging: W is L2-resident (<=256KB), A streams through L3; fragments
// are 16B/lane contiguous in both -> direct global_load_dwordx4, zero barriers.
// Block: 512 thr = 8 waves (2M x 4N), wave = 64x64, BM=128, BN=256(full row).
// MODE 0: relu -> bf16 Hb.   MODE 1: relu -> row-L2-normalize -> fp32 Out.
template<int KTOT, int MODE>
__global__ void __launch_bounds__(512) k_gemm(
    const u16* __restrict__ A0, const u16* __restrict__ A1,
    const u16* __restrict__ B, const float* __restrict__ bias,
    u16* __restrict__ Hb, float* __restrict__ Out, int M)
{
    const int t    = threadIdx.x;
    const int lane = t & 63;
    const int w    = t >> 6;        // 0..7
    const int wm   = w >> 2;        // 0..1  (M dir)
    const int wn   = w & 3;         // 0..3  (N dir)
    const int l15  = lane & 15;
    const int lk8  = (lane >> 4) << 3;   // k sub-offset: 0,8,16,24
    const int rsub = (lane >> 4) << 2;   // C row sub-offset: 0,4,8,12
    const int m0   = blockIdx.x * 128;

    int ra[4];                           // clamped A rows per m-fragment
    #pragma unroll
    for (int fm = 0; fm < 4; ++fm) {
        int r = m0 + wm * 64 + fm * 16 + l15;
        ra[fm] = (r < M) ? r : (M - 1);
    }

    f32x4 acc[4][4];
    #pragma unroll
    for (int i = 0; i < 4; ++i)
        #pragma unroll
        for (int j = 0; j < 4; ++j)
            acc[i][j] = (f32x4)(0.f);

    // B fragment rows: W[wn*64 + fn*16 + l15][k], 16B contiguous per lane
    const u16* bbase = B + (size_t)(wn * 64 + l15) * KTOT + lk8;

    // ---- K loop, first 256 cols from A0 ----
    #pragma unroll
    for (int k0 = 0; k0 < 256; k0 += 32) {
        bf16x8 af[4], bfr[4];
        #pragma unroll
        for (int fm = 0; fm < 4; ++fm)
            af[fm] = *(const bf16x8*)(A0 + (size_t)ra[fm] * 256 + k0 + lk8);
        #pragma unroll
        for (int fn = 0; fn < 4; ++fn)
            bfr[fn] = *(const bf16x8*)(bbase + (size_t)fn * 16 * KTOT + k0);
        #pragma unroll
        for (int fm = 0; fm < 4; ++fm)
            #pragma unroll
            for (int fn = 0; fn < 4; ++fn)
                acc[fm][fn] = __builtin_amdgcn_mfma_f32_16x16x32_bf16(
                    af[fm], bfr[fn], acc[fm][fn], 0, 0, 0);
    }
    // ---- second 256 cols from A1 (KTOT==512 only) ----
    if (KTOT == 512) {
        #pragma unroll
        for (int k0 = 0; k0 < 256; k0 += 32) {
            bf16x8 af[4], bfr[4];
            #pragma unroll
            for (int fm = 0; fm < 4; ++fm)
                af[fm] = *(const bf16x8*)(A1 + (size_t)ra[fm] * 256 + k0 + lk8);
            #pragma unroll
            for (int fn = 0; fn < 4; ++fn)
                bfr[fn] = *(const bf16x8*)(bbase + (size_t)fn * 16 * KTOT + 256 + k0);
            #pragma unroll
            for (int fm = 0; fm < 4; ++fm)
                #pragma unroll
                for (int fn = 0; fn < 4; ++fn)
                    acc[fm][fn] = __builtin_amdgcn_mfma_f32_16x16x32_bf16(
                        af[fm], bfr[fn], acc[fm][fn], 0, 0, 0);
        }
    }

    if (MODE == 0) {
        // relu -> bf16 h
        #pragma unroll
        for (int fn = 0; fn < 4; ++fn) {
            const int col = wn * 64 + fn * 16 + l15;
            const float bv = bias[col];
            #pragma unroll
            for (int fm = 0; fm < 4; ++fm) {
                const int rb = m0 + wm * 64 + fm * 16 + rsub;
                #pragma unroll
                for (int r = 0; r < 4; ++r) {
                    const int row = rb + r;
                    if (row < M) {
                        float v = fmaxf(acc[fm][fn][r] + bv, 0.f);
                        Hb[(size_t)row * 256 + col] = f2bf(v);
                    }
                }
            }
        }
    } else {
        // relu -> row L2-normalize -> fp32 out (BN==256 covers full row)
        __shared__ __align__(16) float sums[128][4];
        float part[4][4];
        #pragma unroll
        for (int fm = 0; fm < 4; ++fm)
            #pragma unroll
            for (int r = 0; r < 4; ++r)
                part[fm][r] = 0.f;

        #pragma unroll
        for (int fn = 0; fn < 4; ++fn) {
            const float bv = bias[wn * 64 + fn * 16 + l15];
            #pragma unroll
            for (int fm = 0; fm < 4; ++fm)
                #pragma unroll
                for (int r = 0; r < 4; ++r) {
                    float v = fmaxf(acc[fm][fn][r] + bv, 0.f);
                    acc[fm][fn][r] = v;
                    part[fm][r] += v * v;
                }
        }
        // sum over the wave's 64 cols (16 col-lanes x 4 fn already in-reg)
        #pragma unroll
        for (int fm = 0; fm < 4; ++fm)
            #pragma unroll
            for (int r = 0; r < 4; ++r) {
                float s = part[fm][r];
                s += __shfl_xor(s, 1, 64);
                s += __shfl_xor(s, 2, 64);
                s += __shfl_xor(s, 4, 64);
                s += __shfl_xor(s, 8, 64);
                part[fm][r] = s;
            }
        // cross-wave (4 N-waves) via LDS
        if (l15 == 0) {
            #pragma unroll
            for (int fm = 0; fm < 4; ++fm)
                #pragma unroll
                for (int r = 0; r < 4; ++r)
                    sums[wm * 64 + fm * 16 + rsub + r][wn] = part[fm][r];
        }
        __syncthreads();
        #pragma unroll
        for (int fm = 0; fm < 4; ++fm) {
            #pragma unroll
            for (int r = 0; r < 4; ++r) {
                const int lrow = wm * 64 + fm * 16 + rsub + r;
                const f32x4 sv = *(const f32x4*)&sums[lrow][0];
                const float tot = sv.x + sv.y + sv.z + sv.w;
                const float scale = 1.f / fmaxf(sqrtf(tot), 1e-12f);
                const int row = m0 + lrow;
                if (row < M) {
                    #pragma unroll
                    for (int fn = 0; fn < 4; ++fn) {
                        const int col = wn * 64 + fn * 16 + l15;
                        Out[(size_t)row * 256 + col] = acc[fm][fn][r] * scale;
                    }
                }
            }
        }
    }
}

extern "C" void kernel_launch(void* const* d_in, const int* in_sizes, int n_in,
                              void* d_out, int out_size, void* d_ws, size_t ws_size,
                              hipStream_t stream)
{
    const float* X         = (const float*)d_in[0];
    const int*   sub_nodes = (const int*)d_in[1];
    const int*   nbr       = (const int*)d_in[2];
    const int*   g2s       = (const int*)d_in[3];
    const float* Wn        = (const float*)d_in[4];
    const float* bn        = (const float*)d_in[5];
    const float* Wf        = (const float*)d_in[6];
    const float* bfin      = (const float*)d_in[7];
    float*       out       = (float*)d_out;

    const int M = out_size / 256;                 // 50000 rows

    // workspace (bf16): Xb | h_b | mean_b | Wnb | Wfb   (~77 MB)
    u16* Xb     = (u16*)d_ws;
    u16* h_b    = Xb     + (size_t)M * 256;
    u16* mean_b = h_b    + (size_t)M * 256;
    u16* Wnb    = mean_b + (size_t)M * 256;
    u16* Wfb    = Wnb    + 65536;

    dim3 b256(256), b512(512);

    k_cast_w<<<768, b256, 0, stream>>>(Wn, Wf, Wnb, Wfb);

    const int rowBlocks = (M + 3) / 4;
    k_gather_mean<<<rowBlocks, b256, 0, stream>>>(X, sub_nodes, nbr, g2s, Xb, mean_b, M);

    const int gBlocks = (M + 127) / 128;
    k_gemm<256, 0><<<gBlocks, b512, 0, stream>>>(mean_b, nullptr, Wnb, bn, h_b, nullptr, M);
    k_gemm<512, 1><<<gBlocks, b512, 0, stream>>>(Xb, h_b, Wfb, bfin, nullptr, out, M);
}

// Round 10
// 204.142 us; speedup vs baseline: 2.3004x; 1.3785x over previous
//
#include <hip/hip_runtime.h>
#include <hip/hip_bf16.h>

#define KNBR 20

typedef unsigned short u16;
typedef __attribute__((ext_vector_type(8))) short bf16x8;   // 8 bf16 = 4 VGPR
typedef __attribute__((ext_vector_type(4))) float f32x4;    // MFMA C/D frag

// ---- runtime index-width detection (proven in round 5) ----
__device__ __forceinline__ bool idx_is64(const unsigned int* w) {
    return (w[1] | w[3] | w[5] | w[7] | w[9] | w[11] | w[13] | w[15]) == 0u;
}
__device__ __forceinline__ int idx_at(const int* p, bool is64, long long i) {
    return is64 ? p[2 * i] : p[i];
}

__device__ __forceinline__ u16 f2bf(float x) {
    union { __hip_bfloat16 b; u16 u; } cv;
    cv.b = __float2bfloat16(x);
    return cv.u;
}
__device__ __forceinline__ float blo2f(unsigned int w) {      // low bf16 -> f32
    union { float f; unsigned int i; } c; c.i = w << 16; return c.f;
}
__device__ __forceinline__ float bhi2f(unsigned int w) {      // high bf16 -> f32
    union { float f; unsigned int i; } c; c.i = w & 0xffff0000u; return c.f;
}

// ---------------- K0a: cast weights fp32 -> bf16 (tiny) ----------------
__global__ void __launch_bounds__(256) k_cast_w(
    const float* __restrict__ Wn, const float* __restrict__ Wf,
    u16* __restrict__ Wnb, u16* __restrict__ Wfb)
{
    int i = blockIdx.x * 256 + threadIdx.x;      // 196608 total
    if (i < 65536)       Wnb[i] = f2bf(Wn[i]);
    else if (i < 196608) Wfb[i - 65536] = f2bf(Wf[i - 65536]);
}

// ---------------- K0b: cast X fp32 -> bf16 (float4 -> ushort4 per thread) ----
__global__ void __launch_bounds__(256) k_cast_x(
    const float* __restrict__ X, u16* __restrict__ Xb, int n4)
{
    int i = blockIdx.x * 256 + threadIdx.x;
    if (i < n4) {
        float4 v = ((const float4*)X)[i];
        ushort4 o;
        o.x = f2bf(v.x); o.y = f2bf(v.y); o.z = f2bf(v.z); o.w = f2bf(v.w);
        ((ushort4*)Xb)[i] = o;
    }
}

// ---------------- K1: gather-mean over bf16 X -> bf16 mean ----------------
// 2 rows per wave: half-wave (32 lanes) x 16B = one 512B bf16 row per gather.
// fp32 accumulation; halves gather traffic vs fp32 X (1 GB -> 512 MB).
__global__ void __launch_bounds__(256) k_gather_mean(
    const u16* __restrict__ Xb, const int* __restrict__ sub_nodes,
    const int* __restrict__ nbr, const int* __restrict__ g2s,
    u16* __restrict__ mean_b, int M)
{
    const bool is64 = idx_is64((const unsigned int*)nbr);
    const int lane = threadIdx.x & 63;
    const int wid  = threadIdx.x >> 6;       // wave in block: 0..3
    const int half = lane >> 5;              // 0/1: which row of the pair
    const int l31  = lane & 31;
    const int row  = blockIdx.x * 8 + wid * 2 + half;
    const int rowc = (row < M) ? row : (M - 1);

    const int g = idx_at(sub_nodes, is64, rowc);
    int s_my = rowc;
    if (l31 < KNBR) {
        int nid = idx_at(nbr, is64, (long long)g * KNBR + l31);
        int s   = idx_at(g2s, is64, nid);
        s_my = (s < 0) ? rowc : s;
    }

    float acc[8] = {0.f, 0.f, 0.f, 0.f, 0.f, 0.f, 0.f, 0.f};
    const int sbase = half << 5;             // shfl source base for this half
    #pragma unroll
    for (int k = 0; k < KNBR; ++k) {
        const int sk = __shfl(s_my, sbase + k, 64);
        const uint4 v = ((const uint4*)(Xb + (size_t)sk * 256))[l31];
        acc[0] += blo2f(v.x); acc[1] += bhi2f(v.x);
        acc[2] += blo2f(v.y); acc[3] += bhi2f(v.y);
        acc[4] += blo2f(v.z); acc[5] += bhi2f(v.z);
        acc[6] += blo2f(v.w); acc[7] += bhi2f(v.w);
    }
    if (row < M) {
        const float inv = 1.0f / (float)KNBR;
        uint4 o;
        o.x = (unsigned)f2bf(acc[0] * inv) | ((unsigned)f2bf(acc[1] * inv) << 16);
        o.y = (unsigned)f2bf(acc[2] * inv) | ((unsigned)f2bf(acc[3] * inv) << 16);
        o.z = (unsigned)f2bf(acc[4] * inv) | ((unsigned)f2bf(acc[5] * inv) << 16);
        o.w = (unsigned)f2bf(acc[6] * inv) | ((unsigned)f2bf(acc[7] * inv) << 16);
        ((uint4*)(mean_b + (size_t)row * 256))[l31] = o;
    }
}

// ---------------- K2/K3: MFMA GEMM  C = relu(A @ W^T + bias) ----------------
// A bf16 [M,KTOT] as halves A0|A1 (row stride 256 each); W bf16 [256,KTOT].
// No LDS staging: W is L2-resident, A streams through L3; fragments are
// 16B/lane contiguous in both -> direct global_load_dwordx4, zero barriers.
// Block: 512 thr = 8 waves (2M x 4N), wave = 64x64, BM=128, BN=256(full row).
// MODE 0: relu -> bf16 Hb.   MODE 1: relu -> row-L2-normalize -> fp32 Out.
template<int KTOT, int MODE>
__global__ void __launch_bounds__(512) k_gemm(
    const u16* __restrict__ A0, const u16* __restrict__ A1,
    const u16* __restrict__ B, const float* __restrict__ bias,
    u16* __restrict__ Hb, float* __restrict__ Out, int M)
{
    const int t    = threadIdx.x;
    const int lane = t & 63;
    const int w    = t >> 6;        // 0..7
    const int wm   = w >> 2;        // 0..1  (M dir)
    const int wn   = w & 3;         // 0..3  (N dir)
    const int l15  = lane & 15;
    const int lk8  = (lane >> 4) << 3;   // k sub-offset: 0,8,16,24
    const int rsub = (lane >> 4) << 2;   // C row sub-offset: 0,4,8,12
    const int m0   = blockIdx.x * 128;

    int ra[4];                           // clamped A rows per m-fragment
    #pragma unroll
    for (int fm = 0; fm < 4; ++fm) {
        int r = m0 + wm * 64 + fm * 16 + l15;
        ra[fm] = (r < M) ? r : (M - 1);
    }

    f32x4 acc[4][4];
    #pragma unroll
    for (int i = 0; i < 4; ++i)
        #pragma unroll
        for (int j = 0; j < 4; ++j)
            acc[i][j] = (f32x4)(0.f);

    // B fragment rows: W[wn*64 + fn*16 + l15][k], 16B contiguous per lane
    const u16* bbase = B + (size_t)(wn * 64 + l15) * KTOT + lk8;

    // ---- K loop, first 256 cols from A0 ----
    #pragma unroll
    for (int k0 = 0; k0 < 256; k0 += 32) {
        bf16x8 af[4], bfr[4];
        #pragma unroll
        for (int fm = 0; fm < 4; ++fm)
            af[fm] = *(const bf16x8*)(A0 + (size_t)ra[fm] * 256 + k0 + lk8);
        #pragma unroll
        for (int fn = 0; fn < 4; ++fn)
            bfr[fn] = *(const bf16x8*)(bbase + (size_t)fn * 16 * KTOT + k0);
        #pragma unroll
        for (int fm = 0; fm < 4; ++fm)
            #pragma unroll
            for (int fn = 0; fn < 4; ++fn)
                acc[fm][fn] = __builtin_amdgcn_mfma_f32_16x16x32_bf16(
                    af[fm], bfr[fn], acc[fm][fn], 0, 0, 0);
    }
    // ---- second 256 cols from A1 (KTOT==512 only) ----
    if (KTOT == 512) {
        #pragma unroll
        for (int k0 = 0; k0 < 256; k0 += 32) {
            bf16x8 af[4], bfr[4];
            #pragma unroll
            for (int fm = 0; fm < 4; ++fm)
                af[fm] = *(const bf16x8*)(A1 + (size_t)ra[fm] * 256 + k0 + lk8);
            #pragma unroll
            for (int fn = 0; fn < 4; ++fn)
                bfr[fn] = *(const bf16x8*)(bbase + (size_t)fn * 16 * KTOT + 256 + k0);
            #pragma unroll
            for (int fm = 0; fm < 4; ++fm)
                #pragma unroll
                for (int fn = 0; fn < 4; ++fn)
                    acc[fm][fn] = __builtin_amdgcn_mfma_f32_16x16x32_bf16(
                        af[fm], bfr[fn], acc[fm][fn], 0, 0, 0);
        }
    }

    if (MODE == 0) {
        // relu -> bf16 h
        #pragma unroll
        for (int fn = 0; fn < 4; ++fn) {
            const int col = wn * 64 + fn * 16 + l15;
            const float bv = bias[col];
            #pragma unroll
            for (int fm = 0; fm < 4; ++fm) {
                const int rb = m0 + wm * 64 + fm * 16 + rsub;
                #pragma unroll
                for (int r = 0; r < 4; ++r) {
                    const int row = rb + r;
                    if (row < M) {
                        float v = fmaxf(acc[fm][fn][r] + bv, 0.f);
                        Hb[(size_t)row * 256 + col] = f2bf(v);
                    }
                }
            }
        }
    } else {
        // relu -> row L2-normalize -> fp32 out (BN==256 covers full row)
        __shared__ __align__(16) float sums[128][4];
        float part[4][4];
        #pragma unroll
        for (int fm = 0; fm < 4; ++fm)
            #pragma unroll
            for (int r = 0; r < 4; ++r)
                part[fm][r] = 0.f;

        #pragma unroll
        for (int fn = 0; fn < 4; ++fn) {
            const float bv = bias[wn * 64 + fn * 16 + l15];
            #pragma unroll
            for (int fm = 0; fm < 4; ++fm)
                #pragma unroll
                for (int r = 0; r < 4; ++r) {
                    float v = fmaxf(acc[fm][fn][r] + bv, 0.f);
                    acc[fm][fn][r] = v;
                    part[fm][r] += v * v;
                }
        }
        // sum over the wave's 64 cols (16 col-lanes x 4 fn already in-reg)
        #pragma unroll
        for (int fm = 0; fm < 4; ++fm)
            #pragma unroll
            for (int r = 0; r < 4; ++r) {
                float s = part[fm][r];
                s += __shfl_xor(s, 1, 64);
                s += __shfl_xor(s, 2, 64);
                s += __shfl_xor(s, 4, 64);
                s += __shfl_xor(s, 8, 64);
                part[fm][r] = s;
            }
        // cross-wave (4 N-waves) via LDS
        if (l15 == 0) {
            #pragma unroll
            for (int fm = 0; fm < 4; ++fm)
                #pragma unroll
                for (int r = 0; r < 4; ++r)
                    sums[wm * 64 + fm * 16 + rsub + r][wn] = part[fm][r];
        }
        __syncthreads();
        #pragma unroll
        for (int fm = 0; fm < 4; ++fm) {
            #pragma unroll
            for (int r = 0; r < 4; ++r) {
                const int lrow = wm * 64 + fm * 16 + rsub + r;
                const f32x4 sv = *(const f32x4*)&sums[lrow][0];
                const float tot = sv.x + sv.y + sv.z + sv.w;
                const float scale = 1.f / fmaxf(sqrtf(tot), 1e-12f);
                const int row = m0 + lrow;
                if (row < M) {
                    #pragma unroll
                    for (int fn = 0; fn < 4; ++fn) {
                        const int col = wn * 64 + fn * 16 + l15;
                        Out[(size_t)row * 256 + col] = acc[fm][fn][r] * scale;
                    }
                }
            }
        }
    }
}

extern "C" void kernel_launch(void* const* d_in, const int* in_sizes, int n_in,
                              void* d_out, int out_size, void* d_ws, size_t ws_size,
                              hipStream_t stream)
{
    const float* X         = (const float*)d_in[0];
    const int*   sub_nodes = (const int*)d_in[1];
    const int*   nbr       = (const int*)d_in[2];
    const int*   g2s       = (const int*)d_in[3];
    const float* Wn        = (const float*)d_in[4];
    const float* bn        = (const float*)d_in[5];
    const float* Wf        = (const float*)d_in[6];
    const float* bfin      = (const float*)d_in[7];
    float*       out       = (float*)d_out;

    const int M = out_size / 256;                 // 50000 rows

    // workspace (bf16): Xb | h_b | mean_b | Wnb | Wfb   (~77 MB)
    u16* Xb     = (u16*)d_ws;
    u16* h_b    = Xb     + (size_t)M * 256;
    u16* mean_b = h_b    + (size_t)M * 256;
    u16* Wnb    = mean_b + (size_t)M * 256;
    u16* Wfb    = Wnb    + 65536;

    dim3 b256(256), b512(512);

    k_cast_w<<<768, b256, 0, stream>>>(Wn, Wf, Wnb, Wfb);

    const int nx4 = M * 64;                       // float4 count of X
    k_cast_x<<<(nx4 + 255) / 256, b256, 0, stream>>>(X, Xb, nx4);

    const int gatherBlocks = (M + 7) / 8;         // 8 rows per 4-wave block
    k_gather_mean<<<gatherBlocks, b256, 0, stream>>>(Xb, sub_nodes, nbr, g2s, mean_b, M);

    const int gBlocks = (M + 127) / 128;
    k_gemm<256, 0><<<gBlocks, b512, 0, stream>>>(mean_b, nullptr, Wnb, bn, h_b, nullptr, M);
    k_gemm<512, 1><<<gBlocks, b512, 0, stream>>>(Xb, h_b, Wfb, bfin, nullptr, out, M);
}